// Round 19
// baseline (119.666 us; speedup 1.0000x reference)
//
#include <hip/hip_runtime.h>
#include <math.h>

#define T_DIM 2048
#define C_DIM 1024
#define B_DIM 8
#define TB    32
#define KROW  72      // bf16 elems per Kc/Qc row (64 + 8 pad)  [fallback kernel]
#define PROW  296     // bf16 elems per P row (288 + 8 pad)

typedef float f32x4 __attribute__((ext_vector_type(4)));
typedef short s16x8 __attribute__((ext_vector_type(8)));

__device__ __forceinline__ unsigned short f2bf(float x) {
    union { float f; unsigned u; } v; v.f = x;
    unsigned r = v.u + 0x7fffu + ((v.u >> 16) & 1u);
    return (unsigned short)(r >> 16);
}
__device__ __forceinline__ unsigned pk2(float a, float b) {
    return (unsigned)f2bf(a) | ((unsigned)f2bf(b) << 16);
}

// async 16B/lane global->LDS DMA (wave-uniform LDS base + lane*16; per-lane global src)
__device__ __forceinline__ void gll16(const void* g, void* l) {
    __builtin_amdgcn_global_load_lds(
        (const __attribute__((address_space(1))) unsigned int*)g,
        (__attribute__((address_space(3))) unsigned int*)l,
        16, 0, 0);
}

// ============ pre-pass A/B: X f32 -> fragment-major bf16 Xt[b][tile][kk][lane][8] ============
// elem = X[b][tile*16+(l&15)][kk*32+(l>>4)*8+j]  [r5/r13-verified; used for BOTH Q and K]
__global__ __launch_bounds__(256)
void tile_x(const float* __restrict__ X, unsigned short* __restrict__ Xt)
{
    const int tile = blockIdx.x;      // 0..127
    const int b    = blockIdx.y;
    const int tid  = threadIdx.x;
    const int w = tid >> 6, l = tid & 63, g = l >> 4, ln = l & 15;
    const float* src_row = X + (size_t)(b * T_DIM + tile * 16 + ln) * C_DIM;
#pragma unroll
    for (int kki = 0; kki < 8; ++kki) {
        const int kk = kki * 4 + w;
        const float4* p = (const float4*)(src_row + kk * 32 + g * 8);
        float4 x = p[0], y = p[1];
        uint4 o;
        o.x = pk2(x.x, x.y); o.y = pk2(x.z, x.w);
        o.z = pk2(y.x, y.y); o.w = pk2(y.z, y.w);
        *(uint4*)(Xt + (size_t)(((b * 128 + tile) * 32 + kk) * 64 + l) * 8) = o;
    }
}

// ============ pre-pass C: V f32 -> bf16, fragment-major Vtt OR row-major Vt (verified) ============
__global__ __launch_bounds__(256)
void transpose_vx(const float* __restrict__ V, unsigned short* __restrict__ out,
                  int frag_mode)
{
    __shared__ float buf[64 * 67];
    const int t0 = blockIdx.x * 64;
    const int c0 = blockIdx.y * 64;
    const int b  = blockIdx.z;
    const float* Vb = V + (size_t)b * T_DIM * C_DIM;

    for (int i = threadIdx.x; i < 64 * 64; i += 256) {
        const int r = i >> 6, c = i & 63;
        buf[r * 67 + c] = Vb[(size_t)(t0 + r) * C_DIM + c0 + c];
    }
    __syncthreads();
    const int t8 = threadIdx.x & 7;   // 8-t segment
    const int cl = threadIdx.x >> 3;  // 0..31
#pragma unroll
    for (int half = 0; half < 2; ++half) {
        const int c_loc = cl + half * 32;
        float v[8];
#pragma unroll
        for (int j = 0; j < 8; ++j) v[j] = buf[(t8 * 8 + j) * 67 + c_loc];
        uint4 o;
        o.x = pk2(v[0], v[1]); o.y = pk2(v[2], v[3]);
        o.z = pk2(v[4], v[5]); o.w = pk2(v[6], v[7]);
        if (frag_mode) {
            const int ct = (c0 + c_loc) >> 4, lnv = c_loc & 15;
            const int g = t8 & 3, sg = (t0 >> 5) + (t8 >> 2);
            *(uint4*)(out + (size_t)(((b * 64 + ct) * 64 + sg) * 64 + g * 16 + lnv) * 8) = o;
        } else {
            *(uint4*)(out + (size_t)(b * C_DIM + c0 + c_loc) * T_DIM + t0 + t8 * 8) = o;
        }
    }
}

// ============ banded attention (r8 verbatim — fastest verified, ~37-43us):
//              ALL operands fragment-major, contiguous 1KB DMA, 32-step phase 3 ============
// 256 thr = 4 waves (th = t-half of 32-row tile, sh = s-half / c-split).
__global__ __launch_bounds__(256, 2)
void attn_band_tiled(const unsigned short* __restrict__ Qt,
                     const unsigned short* __restrict__ Kt,
                     const unsigned short* __restrict__ Vtt,
                     const float* __restrict__ Mask, const int* __restrict__ m_ptr,
                     float* __restrict__ wsrow)
{
    // SMEM map (shorts):  phase1: Kbuf = [0, 20480)  (2 bufs x 20 frags x 512)
    //                     phase2/3: P = [0, 9472); Vbuf = [9728, 30208) (2 x 20 x 512)
    __shared__ __align__(16) short SMEM[30208];   // 60,416 B
    __shared__ float pmax[64], psum[64], red[64];
    short* Kbuf = SMEM;
    short* P    = SMEM;
    short* Vbuf = SMEM + 9728;

    // XCD-bijective swizzle: each XCD owns one batch's contiguous t-range
    const int h = blockIdx.x;
    const int logical = (h & 7) * 64 + (h >> 3);
    const int b  = logical >> 6;
    const int t0 = (logical & 63) * TB;

    const int tid = threadIdx.x;
    const int w = tid >> 6, lane = tid & 63, g = lane >> 4, ln = lane & 15;
    const int th = w >> 1, sh = w & 1;
    const int m  = m_ptr[0];

    const int s_lo = max(0, t0 - m);
    const int s_hi = min(T_DIM - 1, t0 + TB - 1 + m);
    const int sg0  = s_lo >> 5;               // 32-aligned by construction
    const int tq0  = t0 >> 4;

    const unsigned short* Qtb = Qt  + (size_t)b * 128 * 32 * 512;
    const unsigned short* Ktb = Kt  + (size_t)b * 128 * 32 * 512;
    const unsigned short* Vtb = Vtt + (size_t)b * 64 * 64 * 512;

    // ---- phase 1: E = Q.K^T; per kk stage 20 frags (18 K + 2 Q), dbuf, 1 barrier/iter ----
    f32x4 E[9];
    f32x4 zed = {0.f, 0.f, 0.f, 0.f};
#pragma unroll
    for (int i = 0; i < 9; ++i) E[i] = zed;

    // wave w stages frags f = 5w..5w+4; f<18: K tile min(sg0*2+f,127); f>=18: Q tile tq0+(f-18)
#define STAGE1(KN, NB)                                                              \
    {                                                                               \
        short* dstb = Kbuf + (NB) * 10240;                                          \
        _Pragma("unroll")                                                           \
        for (int f5 = 0; f5 < 5; ++f5) {                                            \
            const int f = w * 5 + f5;                                               \
            const unsigned short* gp;                                               \
            if (f < 18) gp = Ktb + ((size_t)(min(sg0 * 2 + f, 127) * 32 + (KN)) * 64 + lane) * 8; \
            else        gp = Qtb + ((size_t)((tq0 + (f - 18)) * 32 + (KN)) * 64 + lane) * 8;      \
            gll16(gp, dstb + f * 512);                                              \
        }                                                                           \
    }

    STAGE1(0, 0);
    __syncthreads();

#pragma unroll 2
    for (int kk = 0; kk < 32; ++kk) {
        const int cur = kk & 1;
        if (kk < 31) STAGE1(kk + 1, cur ^ 1);
        const short* cb = Kbuf + cur * 10240;
        s16x8 aq = *(const s16x8*)(cb + (18 + th) * 512 + lane * 8);
#pragma unroll
        for (int i = 0; i < 9; ++i) {
            s16x8 bk = *(const s16x8*)(cb + (sh * 9 + i) * 512 + lane * 8);
            E[i] = __builtin_amdgcn_mfma_f32_16x16x32_bf16(aq, bk, E[i], 0, 0, 0);
        }
        __syncthreads();
    }

    // ---- phase 2: exact softmax (cross-wave over the two s-halves) ----
    const float scale = 0.03125f;   // 1/sqrt(1024)
    const int rowb = th * 16 + g * 4;
    float lm[4];
#pragma unroll
    for (int r = 0; r < 4; ++r) lm[r] = -INFINITY;
    const int s_base = s_lo + sh * 144 + ln;
#pragma unroll
    for (int i = 0; i < 9; ++i) {
        const int s = s_base + i * 16;
#pragma unroll
        for (int r = 0; r < 4; ++r) {
            const int t = t0 + rowb + r;
            int d = t - s; d = d < 0 ? -d : d;
            const bool valid = (s <= s_hi) && (d <= m);
            float e = valid ? E[i][r] : -INFINITY;
            E[i][r] = e;
            lm[r] = fmaxf(lm[r], e);
        }
    }
#pragma unroll
    for (int r = 0; r < 4; ++r)
#pragma unroll
        for (int dd = 1; dd < 16; dd <<= 1) lm[r] = fmaxf(lm[r], __shfl_xor(lm[r], dd));
    if (ln == 0) {
#pragma unroll
        for (int r = 0; r < 4; ++r) pmax[sh * 32 + rowb + r] = lm[r];
    }
    __syncthreads();
    float Mr[4], sum[4];
#pragma unroll
    for (int r = 0; r < 4; ++r) {
        Mr[r] = fmaxf(pmax[rowb + r], pmax[32 + rowb + r]) * scale;
        sum[r] = 0.f;
    }
#pragma unroll
    for (int i = 0; i < 9; ++i)
#pragma unroll
        for (int r = 0; r < 4; ++r) {
            float e = __expf(E[i][r] * scale - Mr[r]);   // -inf -> 0 exactly
            E[i][r] = e;
            sum[r] += e;
        }
#pragma unroll
    for (int r = 0; r < 4; ++r)
#pragma unroll
        for (int dd = 1; dd < 16; dd <<= 1) sum[r] += __shfl_xor(sum[r], dd);
    if (ln == 0) {
#pragma unroll
        for (int r = 0; r < 4; ++r) psum[sh * 32 + rowb + r] = sum[r];
    }
    __syncthreads();
    float inv[4];
#pragma unroll
    for (int r = 0; r < 4; ++r) inv[r] = 1.0f / (psum[rowb + r] + psum[32 + rowb + r]);
#pragma unroll
    for (int i = 0; i < 9; ++i) {
        const int col = sh * 144 + i * 16 + ln;
#pragma unroll
        for (int r = 0; r < 4; ++r)
            P[(rowb + r) * PROW + col] = (short)f2bf(E[i][r] * inv[r]);
    }
    __syncthreads();

    // ---- phase 3: O = P @ V; per q two staged steps (kg 0-4, 5-8), dbuf, 1 barrier/step ----
    s16x8 pa[9];
#pragma unroll
    for (int kg = 0; kg < 9; ++kg)
        pa[kg] = *(const s16x8*)(P + (th * 16 + ln) * PROW + kg * 32 + g * 8);

    int sgc[9];
#pragma unroll
    for (int kg = 0; kg < 9; ++kg) sgc[kg] = min(sg0 + kg, 63);

    float maskv[4], rmax[4];
#pragma unroll
    for (int r = 0; r < 4; ++r) {
        maskv[r] = Mask[(size_t)b * T_DIM + t0 + rowb + r];
        rmax[r]  = -INFINITY;
    }

    // wave w stages ct = 4q+w, kg in [kgbase, kgbase+KG): slot (w*KG + e)
#define STAGE3(S, NB)                                                               \
    {                                                                               \
        const int q_ = (S) >> 1;                                                    \
        short* dstb = Vbuf + (NB) * 10240;                                          \
        const int ct_ = q_ * 4 + w;                                                 \
        if (((S) & 1) == 0) {                                                       \
            _Pragma("unroll")                                                       \
            for (int e = 0; e < 5; ++e)                                             \
                gll16(Vtb + ((size_t)(ct_ * 64 + sgc[e]) * 64 + lane) * 8,          \
                      dstb + (w * 5 + e) * 512);                                    \
        } else {                                                                    \
            _Pragma("unroll")                                                       \
            for (int e = 0; e < 4; ++e)                                             \
                gll16(Vtb + ((size_t)(ct_ * 64 + sgc[5 + e]) * 64 + lane) * 8,      \
                      dstb + (w * 4 + e) * 512);                                    \
        }                                                                           \
    }

    STAGE3(0, 0);
    __syncthreads();

    f32x4 O0 = zed, O1 = zed;
#pragma unroll 2
    for (int s = 0; s < 32; ++s) {
        const int cur = s & 1;
        if (s < 31) STAGE3(s + 1, cur ^ 1);
        const short* vb = Vbuf + cur * 10240;
        if ((s & 1) == 0) {
            O0 = zed; O1 = zed;
#pragma unroll
            for (int e = 0; e < 5; ++e) {
                s16x8 bv0 = *(const s16x8*)(vb + ((sh * 2    ) * 5 + e) * 512 + lane * 8);
                s16x8 bv1 = *(const s16x8*)(vb + ((sh * 2 + 1) * 5 + e) * 512 + lane * 8);
                O0 = __builtin_amdgcn_mfma_f32_16x16x32_bf16(pa[e], bv0, O0, 0, 0, 0);
                O1 = __builtin_amdgcn_mfma_f32_16x16x32_bf16(pa[e], bv1, O1, 0, 0, 0);
            }
        } else {
#pragma unroll
            for (int e = 0; e < 4; ++e) {
                s16x8 bv0 = *(const s16x8*)(vb + ((sh * 2    ) * 4 + e) * 512 + lane * 8);
                s16x8 bv1 = *(const s16x8*)(vb + ((sh * 2 + 1) * 4 + e) * 512 + lane * 8);
                O0 = __builtin_amdgcn_mfma_f32_16x16x32_bf16(pa[5 + e], bv0, O0, 0, 0, 0);
                O1 = __builtin_amdgcn_mfma_f32_16x16x32_bf16(pa[5 + e], bv1, O1, 0, 0, 0);
            }
#pragma unroll
            for (int r = 0; r < 4; ++r) {
                rmax[r] = fmaxf(rmax[r], O0[r] * maskv[r]);
                rmax[r] = fmaxf(rmax[r], O1[r] * maskv[r]);
            }
        }
        __syncthreads();
    }

#pragma unroll
    for (int r = 0; r < 4; ++r)
#pragma unroll
        for (int dd = 1; dd < 16; dd <<= 1) rmax[r] = fmaxf(rmax[r], __shfl_xor(rmax[r], dd));
    if (ln == 0) {
#pragma unroll
        for (int r = 0; r < 4; ++r) red[sh * 32 + rowb + r] = rmax[r];
    }
    __syncthreads();
    if (tid < 32)
        wsrow[(size_t)b * T_DIM + t0 + tid] = fmaxf(red[tid], red[32 + tid]);
}

// ============ fallback (round-1, verified): K/V staged per block, Vt row-major ============
__global__ __launch_bounds__(256, 2)
void attn_band_mfma(const float* __restrict__ Q, const float* __restrict__ K,
                    const unsigned short* __restrict__ Vt,
                    const float* __restrict__ Mask, const int* __restrict__ m_ptr,
                    float* __restrict__ wsrow)
{
    __shared__ __align__(16) char smem_raw[57600];
    short* SM = (short*)smem_raw;
    short* Kc = SM;
    short* Qc = SM + 288 * KROW;
    short* P  = SM;
    short* Vl = SM + 32 * PROW;
    float* pmax = (float*)(smem_raw + 56832);
    float* psum = pmax + 64;
    float* red  = psum + 64;

    const int h = blockIdx.x;
    const int logical = (h & 7) * 64 + (h >> 3);
    const int b  = logical >> 6;
    const int t0 = (logical & 63) * TB;

    const int tid = threadIdx.x;
    const int w = tid >> 6, lane = tid & 63, g = lane >> 4, ln = lane & 15;
    const int th = w >> 1, sh = w & 1;
    const int m  = m_ptr[0];

    const int s_lo = max(0, t0 - m);
    const int s_hi = min(T_DIM - 1, t0 + TB - 1 + m);

    const float* Qb = Q + (size_t)b * T_DIM * C_DIM;
    const float* Kb = K + (size_t)b * T_DIM * C_DIM;
    const unsigned short* Vtb = Vt + (size_t)b * C_DIM * T_DIM;

    f32x4 E[9];
    f32x4 zed = {0.f, 0.f, 0.f, 0.f};
#pragma unroll
    for (int i = 0; i < 9; ++i) E[i] = zed;

    for (int cc = 0; cc < C_DIM / 64; ++cc) {
        const int c0 = cc * 64;
        __syncthreads();
        for (int u = tid; u < 288 * 8; u += 256) {
            const int su = u >> 3, un = u & 7;
            const int s = min(s_lo + su, T_DIM - 1);
            const float4* src = (const float4*)(Kb + (size_t)s * C_DIM + c0 + un * 8);
            float4 x = src[0], y = src[1];
            uint4 o; o.x = pk2(x.x, x.y); o.y = pk2(x.z, x.w);
            o.z = pk2(y.x, y.y); o.w = pk2(y.z, y.w);
            *(uint4*)(Kc + su * KROW + un * 8) = o;
        }
        {
            const int su = tid >> 3, un = tid & 7;
            const float4* src = (const float4*)(Qb + (size_t)(t0 + su) * C_DIM + c0 + un * 8);
            float4 x = src[0], y = src[1];
            uint4 o; o.x = pk2(x.x, x.y); o.y = pk2(x.z, x.w);
            o.z = pk2(y.x, y.y); o.w = pk2(y.z, y.w);
            *(uint4*)(Qc + su * KROW + un * 8) = o;
        }
        __syncthreads();
        s16x8 aq[2];
#pragma unroll
        for (int kk = 0; kk < 2; ++kk)
            aq[kk] = *(const s16x8*)(Qc + (th * 16 + ln) * KROW + kk * 32 + g * 8);
#pragma unroll
        for (int i = 0; i < 9; ++i) {
            const int srow2 = (sh * 9 + i) * 16 + ln;
#pragma unroll
            for (int kk = 0; kk < 2; ++kk) {
                s16x8 bk = *(const s16x8*)(Kc + srow2 * KROW + kk * 32 + g * 8);
                E[i] = __builtin_amdgcn_mfma_f32_16x16x32_bf16(aq[kk], bk, E[i], 0, 0, 0);
            }
        }
    }

    const float scale = 0.03125f;
    const int rowb = th * 16 + g * 4;
    float lm[4];
#pragma unroll
    for (int r = 0; r < 4; ++r) lm[r] = -INFINITY;
    const int s_base = s_lo + sh * 144 + ln;
#pragma unroll
    for (int i = 0; i < 9; ++i) {
        const int s = s_base + i * 16;
#pragma unroll
        for (int r = 0; r < 4; ++r) {
            const int t = t0 + rowb + r;
            int d = t - s; d = d < 0 ? -d : d;
            const bool valid = (s <= s_hi) && (d <= m);
            float e = valid ? E[i][r] : -INFINITY;
            E[i][r] = e;
            lm[r] = fmaxf(lm[r], e);
        }
    }
#pragma unroll
    for (int r = 0; r < 4; ++r)
#pragma unroll
        for (int dd = 1; dd < 16; dd <<= 1) lm[r] = fmaxf(lm[r], __shfl_xor(lm[r], dd));
    if (ln == 0) {
#pragma unroll
        for (int r = 0; r < 4; ++r) pmax[sh * 32 + rowb + r] = lm[r];
    }
    __syncthreads();
    float Mr[4], sum[4];
#pragma unroll
    for (int r = 0; r < 4; ++r) {
        Mr[r] = fmaxf(pmax[rowb + r], pmax[32 + rowb + r]) * scale;
        sum[r] = 0.f;
    }
#pragma unroll
    for (int i = 0; i < 9; ++i)
#pragma unroll
        for (int r = 0; r < 4; ++r) {
            float e = __expf(E[i][r] * scale - Mr[r]);
            E[i][r] = e;
            sum[r] += e;
        }
#pragma unroll
    for (int r = 0; r < 4; ++r)
#pragma unroll
        for (int dd = 1; dd < 16; dd <<= 1) sum[r] += __shfl_xor(sum[r], dd);
    if (ln == 0) {
#pragma unroll
        for (int r = 0; r < 4; ++r) psum[sh * 32 + rowb + r] = sum[r];
    }
    __syncthreads();
    float inv[4];
#pragma unroll
    for (int r = 0; r < 4; ++r) inv[r] = 1.0f / (psum[rowb + r] + psum[32 + rowb + r]);
#pragma unroll
    for (int i = 0; i < 9; ++i) {
        const int col = sh * 144 + i * 16 + ln;
#pragma unroll
        for (int r = 0; r < 4; ++r)
            P[(rowb + r) * PROW + col] = (short)f2bf(E[i][r] * inv[r]);
    }
    __syncthreads();

    s16x8 pa[9];
#pragma unroll
    for (int kg = 0; kg < 9; ++kg)
        pa[kg] = *(const s16x8*)(P + (th * 16 + ln) * PROW + kg * 32 + g * 8);

    float maskv[4], rmax[4];
#pragma unroll
    for (int r = 0; r < 4; ++r) {
        maskv[r] = Mask[(size_t)b * T_DIM + t0 + rowb + r];
        rmax[r]  = -INFINITY;
    }

    for (int cc = 0; cc < C_DIM / 64; ++cc) {
        __syncthreads();
        for (int i2 = tid; i2 < 64 * 36; i2 += 256) {
            const int cr = i2 / 36, un = i2 - cr * 36;
            const int sb = min(s_lo + un * 8, T_DIM - 8);
            uint4 x = *(const uint4*)(Vtb + (size_t)(cc * 64 + cr) * T_DIM + sb);
            *(uint4*)(Vl + cr * PROW + un * 8) = x;
        }
        __syncthreads();
#pragma unroll
        for (int nbi = 0; nbi < 2; ++nbi) {
            const int crow = sh * 32 + nbi * 16 + ln;
            f32x4 O = zed;
#pragma unroll
            for (int kg = 0; kg < 9; ++kg) {
                s16x8 bv = *(const s16x8*)(Vl + crow * PROW + kg * 32 + g * 8);
                O = __builtin_amdgcn_mfma_f32_16x16x32_bf16(pa[kg], bv, O, 0, 0, 0);
            }
#pragma unroll
            for (int r = 0; r < 4; ++r)
                rmax[r] = fmaxf(rmax[r], O[r] * maskv[r]);
        }
    }
#pragma unroll
    for (int r = 0; r < 4; ++r)
#pragma unroll
        for (int dd = 1; dd < 16; dd <<= 1) rmax[r] = fmaxf(rmax[r], __shfl_xor(rmax[r], dd));
    if (ln == 0) {
#pragma unroll
        for (int r = 0; r < 4; ++r) red[sh * 32 + rowb + r] = rmax[r];
    }
    __syncthreads();
    if (tid < 32)
        wsrow[(size_t)b * T_DIM + t0 + tid] = fmaxf(red[tid], red[32 + tid]);
}

// out[b] = sum_t ws[b][t]
__global__ void reduce_b(const float* __restrict__ ws, float* __restrict__ out)
{
    const int b = blockIdx.x;
    float s = 0.f;
    for (int t = threadIdx.x; t < T_DIM; t += 256) s += ws[(size_t)b * T_DIM + t];
#pragma unroll
    for (int dd = 32; dd > 0; dd >>= 1) s += __shfl_xor(s, dd);
    __shared__ float acc[4];
    if ((threadIdx.x & 63) == 0) acc[threadIdx.x >> 6] = s;
    __syncthreads();
    if (threadIdx.x == 0) out[b] = acc[0] + acc[1] + acc[2] + acc[3];
}

extern "C" void kernel_launch(void* const* d_in, const int* in_sizes, int n_in,
                              void* d_out, int out_size, void* d_ws, size_t ws_size,
                              hipStream_t stream)
{
    const float* Q    = (const float*)d_in[0];
    const float* K    = (const float*)d_in[1];
    const float* V    = (const float*)d_in[2];
    const float* Mask = (const float*)d_in[3];
    const int*   m    = (const int*)d_in[4];
    float* out = (float*)d_out;

    const size_t frag_bytes = (size_t)B_DIM * T_DIM * C_DIM * 2;   // 33,554,432 per tensor
    const size_t need_main  = 3 * frag_bytes + (size_t)B_DIM * T_DIM * 4;

    if (ws_size >= need_main) {
        unsigned short* Qt  = (unsigned short*)d_ws;
        unsigned short* Kt  = (unsigned short*)((char*)d_ws + frag_bytes);
        unsigned short* Vtt = (unsigned short*)((char*)d_ws + 2 * frag_bytes);
        float* wsrow = (float*)((char*)d_ws + 3 * frag_bytes);
        tile_x<<<dim3(128, B_DIM), 256, 0, stream>>>(Q, Qt);    // Q -> fragment-major
        tile_x<<<dim3(128, B_DIM), 256, 0, stream>>>(K, Kt);    // K -> fragment-major
        transpose_vx<<<dim3(T_DIM / 64, C_DIM / 64, B_DIM), 256, 0, stream>>>(V, Vtt, 1);
        attn_band_tiled<<<dim3((T_DIM / TB) * B_DIM), 256, 0, stream>>>(Qt, Kt, Vtt, Mask, m, wsrow);
        reduce_b<<<B_DIM, 256, 0, stream>>>(wsrow, out);
    } else {
        unsigned short* Vt = (unsigned short*)d_ws;
        float* wsrow = (float*)((char*)d_ws + frag_bytes);
        transpose_vx<<<dim3(T_DIM / 64, C_DIM / 64, B_DIM), 256, 0, stream>>>(V, Vt, 0);
        attn_band_mfma<<<dim3((T_DIM / TB) * B_DIM), 256, 0, stream>>>(Q, K, Vt, Mask, m, wsrow);
        reduce_b<<<B_DIM, 256, 0, stream>>>(wsrow, out);
    }
}

// Round 20
// 113.579 us; speedup vs baseline: 1.0536x; 1.0536x over previous
//
#include <hip/hip_runtime.h>
#include <math.h>

#define T_DIM 2048
#define C_DIM 1024
#define B_DIM 8
#define KROW  72      // bf16 elems per Kc/Qc row (64 + 8 pad)  [fallback kernel]
#define PROW  296     // bf16 elems per P row (fallback kernel)
#define P64W  336     // P row width (shorts) in 64-row kernel: 21-slot window

typedef float f32x4 __attribute__((ext_vector_type(4)));
typedef short s16x8 __attribute__((ext_vector_type(8)));

__device__ __forceinline__ unsigned short f2bf(float x) {
    union { float f; unsigned u; } v; v.f = x;
    unsigned r = v.u + 0x7fffu + ((v.u >> 16) & 1u);
    return (unsigned short)(r >> 16);
}
__device__ __forceinline__ unsigned pk2(float a, float b) {
    return (unsigned)f2bf(a) | ((unsigned)f2bf(b) << 16);
}

// async 16B/lane global->LDS DMA (wave-uniform LDS base + lane*16; per-lane global src)
__device__ __forceinline__ void gll16(const void* g, void* l) {
    __builtin_amdgcn_global_load_lds(
        (const __attribute__((address_space(1))) unsigned int*)g,
        (__attribute__((address_space(3))) unsigned int*)l,
        16, 0, 0);
}

// ============ pre-pass A: K f32 -> fragment-major bf16 Kt[b][tile][kk][lane][8] (r13-verified) ============
__global__ __launch_bounds__(256)
void tile_x(const float* __restrict__ X, unsigned short* __restrict__ Xt)
{
    const int tile = blockIdx.x;      // 0..127
    const int b    = blockIdx.y;
    const int tid  = threadIdx.x;
    const int w = tid >> 6, l = tid & 63, g = l >> 4, ln = l & 15;
    const float* src_row = X + (size_t)(b * T_DIM + tile * 16 + ln) * C_DIM;
#pragma unroll
    for (int kki = 0; kki < 8; ++kki) {
        const int kk = kki * 4 + w;
        const float4* p = (const float4*)(src_row + kk * 32 + g * 8);
        float4 x = p[0], y = p[1];
        uint4 o;
        o.x = pk2(x.x, x.y); o.y = pk2(x.z, x.w);
        o.z = pk2(y.x, y.y); o.w = pk2(y.z, y.w);
        *(uint4*)(Xt + (size_t)(((b * 128 + tile) * 32 + kk) * 64 + l) * 8) = o;
    }
}

// ============ pre-pass B: V f32 -> bf16, fragment-major Vtt OR row-major Vt (verified) ============
__global__ __launch_bounds__(256)
void transpose_vx(const float* __restrict__ V, unsigned short* __restrict__ out,
                  int frag_mode)
{
    __shared__ float buf[64 * 67];
    const int t0 = blockIdx.x * 64;
    const int c0 = blockIdx.y * 64;
    const int b  = blockIdx.z;
    const float* Vb = V + (size_t)b * T_DIM * C_DIM;

    for (int i = threadIdx.x; i < 64 * 64; i += 256) {
        const int r = i >> 6, c = i & 63;
        buf[r * 67 + c] = Vb[(size_t)(t0 + r) * C_DIM + c0 + c];
    }
    __syncthreads();
    const int t8 = threadIdx.x & 7;
    const int cl = threadIdx.x >> 3;
#pragma unroll
    for (int half = 0; half < 2; ++half) {
        const int c_loc = cl + half * 32;
        float v[8];
#pragma unroll
        for (int j = 0; j < 8; ++j) v[j] = buf[(t8 * 8 + j) * 67 + c_loc];
        uint4 o;
        o.x = pk2(v[0], v[1]); o.y = pk2(v[2], v[3]);
        o.z = pk2(v[4], v[5]); o.w = pk2(v[6], v[7]);
        if (frag_mode) {
            const int ct = (c0 + c_loc) >> 4, lnv = c_loc & 15;
            const int g = t8 & 3, sg = (t0 >> 5) + (t8 >> 2);
            *(uint4*)(out + (size_t)(((b * 64 + ct) * 64 + sg) * 64 + g * 16 + lnv) * 8) = o;
        } else {
            *(uint4*)(out + (size_t)(b * C_DIM + c0 + c_loc) * T_DIM + t0 + t8 * 8) = o;
        }
    }
}

// ============ banded attention, 64-row blocks: 8 waves, 21-slot K window, Q f32 direct ============
// wave w: th = w>>1 (t-tile 0..3), sh = w&1 (s-half). Band per t-tile = 18 slots th..th+17.
__global__ __launch_bounds__(512, 2)
void attn_band64(const float* __restrict__ Qf,
                 const unsigned short* __restrict__ Kt,
                 const unsigned short* __restrict__ Vtt,
                 const float* __restrict__ Mask, const int* __restrict__ m_ptr,
                 float* __restrict__ wsrow)
{
    // RAW byte map:
    //  phase1: Kbuf = [0, 43008)   (2 bufs x 21 slots x 1KB)
    //          Qf32 = [43008, 59392) (2 bufs x 4 tiles x 2KB)
    //  phase2/3: P = [0, 43008)  (64 x 336 shorts, window-indexed, zero-filled)
    //            Vbuf = [43008, 63488) (2 bufs x 10 slots x 1KB)
    __shared__ __align__(16) char RAW[63488];
    __shared__ float pmax[128], psum[128], red[128];
    short* P = (short*)RAW;

    // XCD-bijective swizzle: 256 blocks = 8 XCD x 32
    const int h = blockIdx.x;
    const int logical = (h & 7) * 32 + (h >> 3);
    const int b  = logical >> 5;
    const int t0 = (logical & 31) * 64;

    const int tid = threadIdx.x;
    const int w = tid >> 6, lane = tid & 63, g = lane >> 4, ln = lane & 15;
    const int th = w >> 1, sh = w & 1;
    const int m  = m_ptr[0];

    const int s_lo = max(0, t0 - m);
    const int s_hi = min(T_DIM - 1, t0 + 63 + m);
    const int st0  = s_lo >> 4;               // 16-row tile index (even)
    const int sg0  = s_lo >> 5;               // 32-row group index

    const float*          Qg  = Qf  + (size_t)b * T_DIM * C_DIM;
    const unsigned short* Ktb = Kt  + (size_t)b * 128 * 32 * 512;
    const unsigned short* Vtb = Vtt + (size_t)b * 64 * 64 * 512;

    // ---- phase 1: E = Q.K^T; per kk stage 21 K slots + 4 Q f32 tiles, dbuf, 1 barrier/iter ----
    f32x4 E[9];
    f32x4 zed = {0.f, 0.f, 0.f, 0.f};
#pragma unroll
    for (int i = 0; i < 9; ++i) E[i] = zed;

    // wave w stages K slots {2w, 2w+1}; waves 3..7 also slot 16+(w-3); every wave 1 Q half.
#define STAGE1(KN, NB)                                                              \
    {                                                                               \
        short* kb = (short*)(RAW + (NB) * 21504);                                   \
        gll16(Ktb + ((size_t)(min(st0 + 2 * w,     127) * 32 + (KN)) * 64 + lane) * 8, \
              kb + (2 * w) * 512);                                                  \
        gll16(Ktb + ((size_t)(min(st0 + 2 * w + 1, 127) * 32 + (KN)) * 64 + lane) * 8, \
              kb + (2 * w + 1) * 512);                                              \
        if (w >= 3) {                                                               \
            const int s2 = 16 + (w - 3);                                            \
            gll16(Ktb + ((size_t)(min(st0 + s2, 127) * 32 + (KN)) * 64 + lane) * 8, \
                  kb + s2 * 512);                                                   \
        }                                                                           \
        {                                                                           \
            const int qt = w >> 1, hh = w & 1;                                      \
            gll16(Qg + (size_t)(t0 + qt * 16 + ln) * C_DIM + (KN) * 32 + g * 8 + hh * 4, \
                  (float*)(RAW + 43008 + (NB) * 8192) + qt * 512 + hh * 256 + lane * 4); \
        }                                                                           \
    }

    STAGE1(0, 0);
    __syncthreads();

#pragma unroll 2
    for (int kk = 0; kk < 32; ++kk) {
        const int cur = kk & 1;
        if (kk < 31) STAGE1(kk + 1, cur ^ 1);
        const short* kb = (const short*)(RAW + cur * 21504);
        const float* qf = (const float*)(RAW + 43008 + cur * 8192);
        f32x4 qlo = *(const f32x4*)(qf + th * 512 + lane * 4);
        f32x4 qhi = *(const f32x4*)(qf + th * 512 + 256 + lane * 4);
        uint4 aqi;
        aqi.x = pk2(qlo[0], qlo[1]); aqi.y = pk2(qlo[2], qlo[3]);
        aqi.z = pk2(qhi[0], qhi[1]); aqi.w = pk2(qhi[2], qhi[3]);
        s16x8 aq = *(s16x8*)&aqi;
#pragma unroll
        for (int i = 0; i < 9; ++i) {
            s16x8 bk = *(const s16x8*)(kb + (th + sh * 9 + i) * 512 + lane * 8);
            E[i] = __builtin_amdgcn_mfma_f32_16x16x32_bf16(aq, bk, E[i], 0, 0, 0);
        }
        __syncthreads();
    }

    // ---- phase 2: exact softmax; each row's 18 slots split across its sh pair ----
    const float scale = 0.03125f;   // 1/sqrt(1024)
    const int rowb = th * 16 + g * 4;
    float lm[4];
#pragma unroll
    for (int r = 0; r < 4; ++r) lm[r] = -INFINITY;
    const int s_base = s_lo + (th + sh * 9) * 16 + ln;
#pragma unroll
    for (int i = 0; i < 9; ++i) {
        const int s = s_base + i * 16;
#pragma unroll
        for (int r = 0; r < 4; ++r) {
            const int t = t0 + rowb + r;
            int d = t - s; d = d < 0 ? -d : d;
            const bool valid = (s <= s_hi) && (d <= m);
            float e = valid ? E[i][r] : -INFINITY;
            E[i][r] = e;
            lm[r] = fmaxf(lm[r], e);
        }
    }
    // zero-fill P (aliases Kbuf; all waves past last Kbuf read via loop-end barrier)
    for (int z = tid; z < 10752; z += 512) ((unsigned*)RAW)[z] = 0u;
#pragma unroll
    for (int r = 0; r < 4; ++r)
#pragma unroll
        for (int dd = 1; dd < 16; dd <<= 1) lm[r] = fmaxf(lm[r], __shfl_xor(lm[r], dd));
    if (ln == 0) {
#pragma unroll
        for (int r = 0; r < 4; ++r) pmax[sh * 64 + rowb + r] = lm[r];
    }
    __syncthreads();
    float Mr[4], sum[4];
#pragma unroll
    for (int r = 0; r < 4; ++r) {
        Mr[r] = fmaxf(pmax[rowb + r], pmax[64 + rowb + r]) * scale;
        sum[r] = 0.f;
    }
#pragma unroll
    for (int i = 0; i < 9; ++i)
#pragma unroll
        for (int r = 0; r < 4; ++r) {
            float e = __expf(E[i][r] * scale - Mr[r]);   // -inf -> 0 exactly
            E[i][r] = e;
            sum[r] += e;
        }
#pragma unroll
    for (int r = 0; r < 4; ++r)
#pragma unroll
        for (int dd = 1; dd < 16; dd <<= 1) sum[r] += __shfl_xor(sum[r], dd);
    if (ln == 0) {
#pragma unroll
        for (int r = 0; r < 4; ++r) psum[sh * 64 + rowb + r] = sum[r];
    }
    __syncthreads();
    float inv[4];
#pragma unroll
    for (int r = 0; r < 4; ++r) inv[r] = 1.0f / (psum[rowb + r] + psum[64 + rowb + r]);
#pragma unroll
    for (int i = 0; i < 9; ++i) {
        const int col = (th + sh * 9 + i) * 16 + ln;   // window-indexed, <= 335
#pragma unroll
        for (int r = 0; r < 4; ++r)
            P[(rowb + r) * P64W + col] = (short)f2bf(E[i][r] * inv[r]);
    }
    __syncthreads();

    // ---- phase 3: O = P @ V; 64 steps (q = S>>1, kg-half = S&1), 10-slot dbuf ----
    s16x8 pa[10];
#pragma unroll
    for (int kg = 0; kg < 10; ++kg)
        pa[kg] = *(const s16x8*)(P + (th * 16 + ln) * P64W + kg * 32 + g * 8);

    float maskv[4], rmax[4];
#pragma unroll
    for (int r = 0; r < 4; ++r) {
        maskv[r] = Mask[(size_t)b * T_DIM + t0 + rowb + r];
        rmax[r]  = -INFINITY;
    }

    // step S stages 10 frags: slot j -> (ct = (j/5)*32 + q, sg = sg0 + (S&1)*5 + j%5)
#define STAGE3(S, NB)                                                               \
    {                                                                               \
        const int q_ = (S) >> 1, kh_ = (S) & 1;                                     \
        short* vb = (short*)(RAW + 43008 + (NB) * 10240);                           \
        {                                                                           \
            const int shh = w / 5, e = w % 5;                                       \
            gll16(Vtb + ((size_t)((shh * 32 + q_) * 64 + min(sg0 + kh_ * 5 + e, 63)) * 64 + lane) * 8, \
                  vb + w * 512);                                                    \
        }                                                                           \
        if (w < 2) {                                                                \
            const int j2 = 8 + w;                                                   \
            gll16(Vtb + ((size_t)((32 + q_) * 64 + min(sg0 + kh_ * 5 + (j2 - 5), 63)) * 64 + lane) * 8, \
                  vb + j2 * 512);                                                   \
        }                                                                           \
    }

    STAGE3(0, 0);
    __syncthreads();

    f32x4 O0 = zed;
#pragma unroll 2
    for (int S = 0; S < 64; ++S) {
        const int cur = S & 1;
        if (S < 63) STAGE3(S + 1, cur ^ 1);
        const short* vb = (const short*)(RAW + 43008 + cur * 10240);
        const int kh = S & 1;
        if (kh == 0) O0 = zed;
#pragma unroll
        for (int e = 0; e < 5; ++e) {
            s16x8 bv = *(const s16x8*)(vb + (sh * 5 + e) * 512 + lane * 8);
            O0 = __builtin_amdgcn_mfma_f32_16x16x32_bf16(pa[kh * 5 + e], bv, O0, 0, 0, 0);
        }
        if (kh == 1) {
#pragma unroll
            for (int r = 0; r < 4; ++r)
                rmax[r] = fmaxf(rmax[r], O0[r] * maskv[r]);
        }
        __syncthreads();
    }

#pragma unroll
    for (int r = 0; r < 4; ++r)
#pragma unroll
        for (int dd = 1; dd < 16; dd <<= 1) rmax[r] = fmaxf(rmax[r], __shfl_xor(rmax[r], dd));
    if (ln == 0) {
#pragma unroll
        for (int r = 0; r < 4; ++r) red[sh * 64 + rowb + r] = rmax[r];
    }
    __syncthreads();
    if (tid < 64)
        wsrow[(size_t)b * T_DIM + t0 + tid] = fmaxf(red[tid], red[64 + tid]);
}

// ============ fallback (round-1, verified): K/V staged per block, Vt row-major ============
__global__ __launch_bounds__(256, 2)
void attn_band_mfma(const float* __restrict__ Q, const float* __restrict__ K,
                    const unsigned short* __restrict__ Vt,
                    const float* __restrict__ Mask, const int* __restrict__ m_ptr,
                    float* __restrict__ wsrow)
{
    __shared__ __align__(16) char smem_raw[57600];
    short* SM = (short*)smem_raw;
    short* Kc = SM;
    short* Qc = SM + 288 * KROW;
    short* P  = SM;
    short* Vl = SM + 32 * PROW;
    float* pmax = (float*)(smem_raw + 56832);
    float* psum = pmax + 64;
    float* red  = psum + 64;

    const int h = blockIdx.x;
    const int logical = (h & 7) * 64 + (h >> 3);
    const int b  = logical >> 6;
    const int t0 = (logical & 63) * 32;

    const int tid = threadIdx.x;
    const int w = tid >> 6, lane = tid & 63, g = lane >> 4, ln = lane & 15;
    const int th = w >> 1, sh = w & 1;
    const int m  = m_ptr[0];

    const int s_lo = max(0, t0 - m);
    const int s_hi = min(T_DIM - 1, t0 + 31 + m);

    const float* Qb = Q + (size_t)b * T_DIM * C_DIM;
    const float* Kb = K + (size_t)b * T_DIM * C_DIM;
    const unsigned short* Vtb = Vt + (size_t)b * C_DIM * T_DIM;

    f32x4 E[9];
    f32x4 zed = {0.f, 0.f, 0.f, 0.f};
#pragma unroll
    for (int i = 0; i < 9; ++i) E[i] = zed;

    for (int cc = 0; cc < C_DIM / 64; ++cc) {
        const int c0 = cc * 64;
        __syncthreads();
        for (int u = tid; u < 288 * 8; u += 256) {
            const int su = u >> 3, un = u & 7;
            const int s = min(s_lo + su, T_DIM - 1);
            const float4* src = (const float4*)(Kb + (size_t)s * C_DIM + c0 + un * 8);
            float4 x = src[0], y = src[1];
            uint4 o; o.x = pk2(x.x, x.y); o.y = pk2(x.z, x.w);
            o.z = pk2(y.x, y.y); o.w = pk2(y.z, y.w);
            *(uint4*)(Kc + su * KROW + un * 8) = o;
        }
        {
            const int su = tid >> 3, un = tid & 7;
            const float4* src = (const float4*)(Qb + (size_t)(t0 + su) * C_DIM + c0 + un * 8);
            float4 x = src[0], y = src[1];
            uint4 o; o.x = pk2(x.x, x.y); o.y = pk2(x.z, x.w);
            o.z = pk2(y.x, y.y); o.w = pk2(y.z, y.w);
            *(uint4*)(Qc + su * KROW + un * 8) = o;
        }
        __syncthreads();
        s16x8 aq[2];
#pragma unroll
        for (int kk = 0; kk < 2; ++kk)
            aq[kk] = *(const s16x8*)(Qc + (th * 16 + ln) * KROW + kk * 32 + g * 8);
#pragma unroll
        for (int i = 0; i < 9; ++i) {
            const int srow2 = (sh * 9 + i) * 16 + ln;
#pragma unroll
            for (int kk = 0; kk < 2; ++kk) {
                s16x8 bk = *(const s16x8*)(Kc + srow2 * KROW + kk * 32 + g * 8);
                E[i] = __builtin_amdgcn_mfma_f32_16x16x32_bf16(aq[kk], bk, E[i], 0, 0, 0);
            }
        }
    }

    const float scale = 0.03125f;
    const int rowb = th * 16 + g * 4;
    float lm[4];
#pragma unroll
    for (int r = 0; r < 4; ++r) lm[r] = -INFINITY;
    const int s_base = s_lo + sh * 144 + ln;
#pragma unroll
    for (int i = 0; i < 9; ++i) {
        const int s = s_base + i * 16;
#pragma unroll
        for (int r = 0; r < 4; ++r) {
            const int t = t0 + rowb + r;
            int d = t - s; d = d < 0 ? -d : d;
            const bool valid = (s <= s_hi) && (d <= m);
            float e = valid ? E[i][r] : -INFINITY;
            E[i][r] = e;
            lm[r] = fmaxf(lm[r], e);
        }
    }
#pragma unroll
    for (int r = 0; r < 4; ++r)
#pragma unroll
        for (int dd = 1; dd < 16; dd <<= 1) lm[r] = fmaxf(lm[r], __shfl_xor(lm[r], dd));
    if (ln == 0) {
#pragma unroll
        for (int r = 0; r < 4; ++r) pmax[sh * 32 + rowb + r] = lm[r];
    }
    __syncthreads();
    float Mr[4], sum[4];
#pragma unroll
    for (int r = 0; r < 4; ++r) {
        Mr[r] = fmaxf(pmax[rowb + r], pmax[32 + rowb + r]) * scale;
        sum[r] = 0.f;
    }
#pragma unroll
    for (int i = 0; i < 9; ++i)
#pragma unroll
        for (int r = 0; r < 4; ++r) {
            float e = __expf(E[i][r] * scale - Mr[r]);
            E[i][r] = e;
            sum[r] += e;
        }
#pragma unroll
    for (int r = 0; r < 4; ++r)
#pragma unroll
        for (int dd = 1; dd < 16; dd <<= 1) sum[r] += __shfl_xor(sum[r], dd);
    if (ln == 0) {
#pragma unroll
        for (int r = 0; r < 4; ++r) psum[sh * 32 + rowb + r] = sum[r];
    }
    __syncthreads();
    float inv[4];
#pragma unroll
    for (int r = 0; r < 4; ++r) inv[r] = 1.0f / (psum[rowb + r] + psum[32 + rowb + r]);
#pragma unroll
    for (int i = 0; i < 9; ++i) {
        const int col = sh * 144 + i * 16 + ln;
#pragma unroll
        for (int r = 0; r < 4; ++r)
            P[(rowb + r) * PROW + col] = (short)f2bf(E[i][r] * inv[r]);
    }
    __syncthreads();

    s16x8 pa[9];
#pragma unroll
    for (int kg = 0; kg < 9; ++kg)
        pa[kg] = *(const s16x8*)(P + (th * 16 + ln) * PROW + kg * 32 + g * 8);

    float maskv[4], rmax[4];
#pragma unroll
    for (int r = 0; r < 4; ++r) {
        maskv[r] = Mask[(size_t)b * T_DIM + t0 + rowb + r];
        rmax[r]  = -INFINITY;
    }

    for (int cc = 0; cc < C_DIM / 64; ++cc) {
        __syncthreads();
        for (int i2 = tid; i2 < 64 * 36; i2 += 256) {
            const int cr = i2 / 36, un = i2 - cr * 36;
            const int sb = min(s_lo + un * 8, T_DIM - 8);
            uint4 x = *(const uint4*)(Vtb + (size_t)(cc * 64 + cr) * T_DIM + sb);
            *(uint4*)(Vl + cr * PROW + un * 8) = x;
        }
        __syncthreads();
#pragma unroll
        for (int nbi = 0; nbi < 2; ++nbi) {
            const int crow = sh * 32 + nbi * 16 + ln;
            f32x4 O = zed;
#pragma unroll
            for (int kg = 0; kg < 9; ++kg) {
                s16x8 bv = *(const s16x8*)(Vl + crow * PROW + kg * 32 + g * 8);
                O = __builtin_amdgcn_mfma_f32_16x16x32_bf16(pa[kg], bv, O, 0, 0, 0);
            }
#pragma unroll
            for (int r = 0; r < 4; ++r)
                rmax[r] = fmaxf(rmax[r], O[r] * maskv[r]);
        }
    }
#pragma unroll
    for (int r = 0; r < 4; ++r)
#pragma unroll
        for (int dd = 1; dd < 16; dd <<= 1) rmax[r] = fmaxf(rmax[r], __shfl_xor(rmax[r], dd));
    if (ln == 0) {
#pragma unroll
        for (int r = 0; r < 4; ++r) red[sh * 32 + rowb + r] = rmax[r];
    }
    __syncthreads();
    if (tid < 32)
        wsrow[(size_t)b * T_DIM + t0 + tid] = fmaxf(red[tid], red[32 + tid]);
}

// out[b] = sum_t ws[b][t]
__global__ void reduce_b(const float* __restrict__ ws, float* __restrict__ out)
{
    const int b = blockIdx.x;
    float s = 0.f;
    for (int t = threadIdx.x; t < T_DIM; t += 256) s += ws[(size_t)b * T_DIM + t];
#pragma unroll
    for (int dd = 32; dd > 0; dd >>= 1) s += __shfl_xor(s, dd);
    __shared__ float acc[4];
    if ((threadIdx.x & 63) == 0) acc[threadIdx.x >> 6] = s;
    __syncthreads();
    if (threadIdx.x == 0) out[b] = acc[0] + acc[1] + acc[2] + acc[3];
}

extern "C" void kernel_launch(void* const* d_in, const int* in_sizes, int n_in,
                              void* d_out, int out_size, void* d_ws, size_t ws_size,
                              hipStream_t stream)
{
    const float* Q    = (const float*)d_in[0];
    const float* K    = (const float*)d_in[1];
    const float* V    = (const float*)d_in[2];
    const float* Mask = (const float*)d_in[3];
    const int*   m    = (const int*)d_in[4];
    float* out = (float*)d_out;

    const size_t frag_bytes = (size_t)B_DIM * T_DIM * C_DIM * 2;   // 33,554,432 per tensor
    const size_t need_main  = 2 * frag_bytes + (size_t)B_DIM * T_DIM * 4;

    if (ws_size >= need_main) {
        unsigned short* Kt  = (unsigned short*)d_ws;
        unsigned short* Vtt = (unsigned short*)((char*)d_ws + frag_bytes);
        float* wsrow = (float*)((char*)d_ws + 2 * frag_bytes);
        tile_x<<<dim3(128, B_DIM), 256, 0, stream>>>(K, Kt);
        transpose_vx<<<dim3(T_DIM / 64, C_DIM / 64, B_DIM), 256, 0, stream>>>(V, Vtt, 1);
        attn_band64<<<dim3(256), 512, 0, stream>>>(Q, Kt, Vtt, Mask, m, wsrow);
        reduce_b<<<B_DIM, 256, 0, stream>>>(wsrow, out);
    } else {
        unsigned short* Vt = (unsigned short*)d_ws;
        float* wsrow = (float*)((char*)d_ws + frag_bytes);
        transpose_vx<<<dim3(T_DIM / 64, C_DIM / 64, B_DIM), 256, 0, stream>>>(V, Vt, 0);
        attn_band_mfma<<<dim3((T_DIM / 32) * B_DIM), 256, 0, stream>>>(Q, K, Vt, Mask, m, wsrow);
        reduce_b<<<B_DIM, 256, 0, stream>>>(wsrow, out);
    }
}

// Round 21
// 100.837 us; speedup vs baseline: 1.1867x; 1.1264x over previous
//
#include <hip/hip_runtime.h>
#include <math.h>

#define T_DIM 2048
#define C_DIM 1024
#define B_DIM 8
#define TB    32
#define KROW  72      // bf16 elems per Kc/Qc row (64 + 8 pad)  [fallback kernel]
#define PROW  296     // bf16 elems per P row (288 + 8 pad)

typedef float f32x4 __attribute__((ext_vector_type(4)));
typedef short s16x8 __attribute__((ext_vector_type(8)));

__device__ __forceinline__ unsigned short f2bf(float x) {
    union { float f; unsigned u; } v; v.f = x;
    unsigned r = v.u + 0x7fffu + ((v.u >> 16) & 1u);
    return (unsigned short)(r >> 16);
}
__device__ __forceinline__ unsigned pk2(float a, float b) {
    return (unsigned)f2bf(a) | ((unsigned)f2bf(b) << 16);
}

// async 16B/lane global->LDS DMA. LDS dest = wave-uniform base + lane*16 (linear);
// global SOURCE is per-lane.
__device__ __forceinline__ void gll16(const void* g, void* l) {
    __builtin_amdgcn_global_load_lds(
        (const __attribute__((address_space(1))) unsigned int*)g,
        (__attribute__((address_space(3))) unsigned int*)l,
        16, 0, 0);
}

// ============ pre-pass A: K f32 -> fragment-major bf16 Kt[b][tile][kk][lane][8] ============
// elem = K[b][tile*16+(l&15)][kk*32+(l>>4)*8+j]  [r5-verified]
__global__ __launch_bounds__(256)
void tile_k(const float* __restrict__ K, unsigned short* __restrict__ Kt)
{
    const int tile = blockIdx.x;      // 0..127
    const int b    = blockIdx.y;
    const int tid  = threadIdx.x;
    const int w = tid >> 6, l = tid & 63, g = l >> 4, ln = l & 15;
    const float* src_row = K + (size_t)(b * T_DIM + tile * 16 + ln) * C_DIM;
#pragma unroll
    for (int kki = 0; kki < 8; ++kki) {
        const int kk = kki * 4 + w;
        const float4* p = (const float4*)(src_row + kk * 32 + g * 8);
        float4 x = p[0], y = p[1];
        uint4 o;
        o.x = pk2(x.x, x.y); o.y = pk2(x.z, x.w);
        o.z = pk2(y.x, y.y); o.w = pk2(y.z, y.w);
        *(uint4*)(Kt + (size_t)(((b * 128 + tile) * 32 + kk) * 64 + l) * 8) = o;
    }
}

// ============ pre-pass B: V f32 -> bf16, fragment-major Vtt OR row-major Vt (verified) ============
__global__ __launch_bounds__(256)
void transpose_vx(const float* __restrict__ V, unsigned short* __restrict__ out,
                  int frag_mode)
{
    __shared__ float buf[64 * 67];
    const int t0 = blockIdx.x * 64;
    const int c0 = blockIdx.y * 64;
    const int b  = blockIdx.z;
    const float* Vb = V + (size_t)b * T_DIM * C_DIM;

    for (int i = threadIdx.x; i < 64 * 64; i += 256) {
        const int r = i >> 6, c = i & 63;
        buf[r * 67 + c] = Vb[(size_t)(t0 + r) * C_DIM + c0 + c];
    }
    __syncthreads();
    const int t8 = threadIdx.x & 7;   // 8-t segment
    const int cl = threadIdx.x >> 3;  // 0..31
#pragma unroll
    for (int half = 0; half < 2; ++half) {
        const int c_loc = cl + half * 32;
        float v[8];
#pragma unroll
        for (int j = 0; j < 8; ++j) v[j] = buf[(t8 * 8 + j) * 67 + c_loc];
        uint4 o;
        o.x = pk2(v[0], v[1]); o.y = pk2(v[2], v[3]);
        o.z = pk2(v[4], v[5]); o.w = pk2(v[6], v[7]);
        if (frag_mode) {
            const int ct = (c0 + c_loc) >> 4, lnv = c_loc & 15;
            const int g = t8 & 3, sg = (t0 >> 5) + (t8 >> 2);
            *(uint4*)(out + (size_t)(((b * 64 + ct) * 64 + sg) * 64 + g * 16 + lnv) * 8) = o;
        } else {
            *(uint4*)(out + (size_t)(b * C_DIM + c0 + c_loc) * T_DIM + t0 + t8 * 8) = o;
        }
    }
}

// ============ banded attention: Kt fragment-major (contiguous DMA) + Q f32 staged (r13, 101.0us verified) ============
// 256 thr = 4 waves (th = t-half of 32-row tile, sh = s-half / c-split).
__global__ __launch_bounds__(256, 2)
void attn_band_tiled(const float* __restrict__ Q,
                     const unsigned short* __restrict__ Kt,
                     const unsigned short* __restrict__ Vtt,
                     const float* __restrict__ Mask, const int* __restrict__ m_ptr,
                     float* __restrict__ wsrow)
{
    // byte map: phase1: Kbuf = [0, 36864) (2 x 18 frags x 1KB), Qbuf = [36864, 45056) (2 x 4KB)
    //           phase2/3: P = [0, 18944); Vbuf = [19456, 60416) (2 x 20 x 1KB)
    __shared__ __align__(16) char RAW[60416];
    __shared__ float pmax[64], psum[64], red[64];
    short* P = (short*)RAW;

    // XCD-bijective swizzle: each XCD owns one batch's contiguous t-range
    const int h = blockIdx.x;
    const int logical = (h & 7) * 64 + (h >> 3);
    const int b  = logical >> 6;
    const int t0 = (logical & 63) * TB;

    const int tid = threadIdx.x;
    const int w = tid >> 6, lane = tid & 63, g = lane >> 4, ln = lane & 15;
    const int th = w >> 1, sh = w & 1;
    const int m  = m_ptr[0];

    const int s_lo = max(0, t0 - m);
    const int s_hi = min(T_DIM - 1, t0 + TB - 1 + m);
    const int sg0  = s_lo >> 5;               // 32-aligned by construction

    const float*          Qg  = Q   + (size_t)b * T_DIM * C_DIM;
    const unsigned short* Ktb = Kt  + (size_t)b * 128 * 32 * 512;
    const unsigned short* Vtb = Vtt + (size_t)b * 64 * 64 * 512;

    // ---- phase 1: E = Q.K^T ----
    f32x4 E[9];
    f32x4 zed = {0.f, 0.f, 0.f, 0.f};
#pragma unroll
    for (int i = 0; i < 9; ++i) E[i] = zed;

    // wave w: K frags f = 5w..5w+4 (f<18) CONTIGUOUS from fragment-major Kt;
    //         plus one Q f32 call: tile tt=w>>1, half hh=w&1 (4 slots x 1KB, lane-linear).
#define STAGE1(KN, NB)                                                               \
    {                                                                                \
        short* kd = (short*)(RAW) + (NB) * 9216;                                     \
        _Pragma("unroll")                                                            \
        for (int f5 = 0; f5 < 5; ++f5) {                                             \
            const int f = w * 5 + f5;                                                \
            if (f < 18) {                                                            \
                const int ktile = min(sg0 * 2 + f, 127);                             \
                gll16(Ktb + ((size_t)(ktile * 32 + (KN)) * 64 + lane) * 8,           \
                      kd + f * 512);                                                 \
            }                                                                        \
        }                                                                            \
        {                                                                            \
            const int tt = w >> 1, hh = w & 1;                                       \
            const float* qs = Qg + (size_t)(t0 + tt * 16 + ln) * C_DIM               \
                                 + (KN) * 32 + g * 8 + hh * 4;                       \
            gll16(qs, (float*)(RAW + 36864) + (NB) * 1024 + (tt * 2 + hh) * 256);    \
        }                                                                            \
    }

    STAGE1(0, 0);
    __syncthreads();

#pragma unroll 2
    for (int kk = 0; kk < 32; ++kk) {
        const int cur = kk & 1;
        if (kk < 31) STAGE1(kk + 1, cur ^ 1);
        const short* cb = (const short*)(RAW) + cur * 9216;
        const float* qb = (const float*)(RAW + 36864) + cur * 1024;
        f32x4 qlo = *(const f32x4*)(qb + (th * 2    ) * 256 + lane * 4);
        f32x4 qhi = *(const f32x4*)(qb + (th * 2 + 1) * 256 + lane * 4);
        uint4 aqi;
        aqi.x = pk2(qlo[0], qlo[1]); aqi.y = pk2(qlo[2], qlo[3]);
        aqi.z = pk2(qhi[0], qhi[1]); aqi.w = pk2(qhi[2], qhi[3]);
        s16x8 aq = *(s16x8*)&aqi;
#pragma unroll
        for (int i = 0; i < 9; ++i) {
            s16x8 bk = *(const s16x8*)(cb + (sh * 9 + i) * 512 + lane * 8);
            E[i] = __builtin_amdgcn_mfma_f32_16x16x32_bf16(aq, bk, E[i], 0, 0, 0);
        }
        __syncthreads();
    }

    // ---- phase 2: exact softmax (cross-wave over the two s-halves) ----
    const float scale = 0.03125f;   // 1/sqrt(1024)
    const int rowb = th * 16 + g * 4;
    float lm[4];
#pragma unroll
    for (int r = 0; r < 4; ++r) lm[r] = -INFINITY;
    const int s_base = s_lo + sh * 144 + ln;
#pragma unroll
    for (int i = 0; i < 9; ++i) {
        const int s = s_base + i * 16;
#pragma unroll
        for (int r = 0; r < 4; ++r) {
            const int t = t0 + rowb + r;
            int d = t - s; d = d < 0 ? -d : d;
            const bool valid = (s <= s_hi) && (d <= m);
            float e = valid ? E[i][r] : -INFINITY;
            E[i][r] = e;
            lm[r] = fmaxf(lm[r], e);
        }
    }
#pragma unroll
    for (int r = 0; r < 4; ++r)
#pragma unroll
        for (int dd = 1; dd < 16; dd <<= 1) lm[r] = fmaxf(lm[r], __shfl_xor(lm[r], dd));
    if (ln == 0) {
#pragma unroll
        for (int r = 0; r < 4; ++r) pmax[sh * 32 + rowb + r] = lm[r];
    }
    __syncthreads();
    float Mr[4], sum[4];
#pragma unroll
    for (int r = 0; r < 4; ++r) {
        Mr[r] = fmaxf(pmax[rowb + r], pmax[32 + rowb + r]) * scale;
        sum[r] = 0.f;
    }
#pragma unroll
    for (int i = 0; i < 9; ++i)
#pragma unroll
        for (int r = 0; r < 4; ++r) {
            float e = __expf(E[i][r] * scale - Mr[r]);   // -inf -> 0 exactly
            E[i][r] = e;
            sum[r] += e;
        }
#pragma unroll
    for (int r = 0; r < 4; ++r)
#pragma unroll
        for (int dd = 1; dd < 16; dd <<= 1) sum[r] += __shfl_xor(sum[r], dd);
    if (ln == 0) {
#pragma unroll
        for (int r = 0; r < 4; ++r) psum[sh * 32 + rowb + r] = sum[r];
    }
    __syncthreads();
    float inv[4];
#pragma unroll
    for (int r = 0; r < 4; ++r) inv[r] = 1.0f / (psum[rowb + r] + psum[32 + rowb + r]);
#pragma unroll
    for (int i = 0; i < 9; ++i) {
        const int col = sh * 144 + i * 16 + ln;
#pragma unroll
        for (int r = 0; r < 4; ++r)
            P[(rowb + r) * PROW + col] = (short)f2bf(E[i][r] * inv[r]);
    }
    __syncthreads();

    // ---- phase 3: O = P @ V; per q two staged steps (kg 0-4, 5-8), dbuf, 1 barrier/step ----
    short* Vbuf = (short*)(RAW + 19456);
    s16x8 pa[9];
#pragma unroll
    for (int kg = 0; kg < 9; ++kg)
        pa[kg] = *(const s16x8*)(P + (th * 16 + ln) * PROW + kg * 32 + g * 8);

    int sgc[9];
#pragma unroll
    for (int kg = 0; kg < 9; ++kg) sgc[kg] = min(sg0 + kg, 63);

    float maskv[4], rmax[4];
#pragma unroll
    for (int r = 0; r < 4; ++r) {
        maskv[r] = Mask[(size_t)b * T_DIM + t0 + rowb + r];
        rmax[r]  = -INFINITY;
    }

    // wave w stages ct = 4q+w, kg in [kgbase, kgbase+KG): slot (w*KG + e)
#define STAGE3(S, NB)                                                               \
    {                                                                               \
        const int q_ = (S) >> 1;                                                    \
        short* dstb = Vbuf + (NB) * 10240;                                          \
        const int ct_ = q_ * 4 + w;                                                 \
        if (((S) & 1) == 0) {                                                       \
            _Pragma("unroll")                                                       \
            for (int e = 0; e < 5; ++e)                                             \
                gll16(Vtb + ((size_t)(ct_ * 64 + sgc[e]) * 64 + lane) * 8,          \
                      dstb + (w * 5 + e) * 512);                                    \
        } else {                                                                    \
            _Pragma("unroll")                                                       \
            for (int e = 0; e < 4; ++e)                                             \
                gll16(Vtb + ((size_t)(ct_ * 64 + sgc[5 + e]) * 64 + lane) * 8,      \
                      dstb + (w * 4 + e) * 512);                                    \
        }                                                                           \
    }

    STAGE3(0, 0);
    __syncthreads();

    f32x4 O0 = zed, O1 = zed;
#pragma unroll 2
    for (int s = 0; s < 32; ++s) {
        const int cur = s & 1;
        if (s < 31) STAGE3(s + 1, cur ^ 1);
        const short* vb = Vbuf + cur * 10240;
        if ((s & 1) == 0) {
            O0 = zed; O1 = zed;
#pragma unroll
            for (int e = 0; e < 5; ++e) {
                s16x8 bv0 = *(const s16x8*)(vb + ((sh * 2    ) * 5 + e) * 512 + lane * 8);
                s16x8 bv1 = *(const s16x8*)(vb + ((sh * 2 + 1) * 5 + e) * 512 + lane * 8);
                O0 = __builtin_amdgcn_mfma_f32_16x16x32_bf16(pa[e], bv0, O0, 0, 0, 0);
                O1 = __builtin_amdgcn_mfma_f32_16x16x32_bf16(pa[e], bv1, O1, 0, 0, 0);
            }
        } else {
#pragma unroll
            for (int e = 0; e < 4; ++e) {
                s16x8 bv0 = *(const s16x8*)(vb + ((sh * 2    ) * 4 + e) * 512 + lane * 8);
                s16x8 bv1 = *(const s16x8*)(vb + ((sh * 2 + 1) * 4 + e) * 512 + lane * 8);
                O0 = __builtin_amdgcn_mfma_f32_16x16x32_bf16(pa[5 + e], bv0, O0, 0, 0, 0);
                O1 = __builtin_amdgcn_mfma_f32_16x16x32_bf16(pa[5 + e], bv1, O1, 0, 0, 0);
            }
#pragma unroll
            for (int r = 0; r < 4; ++r) {
                rmax[r] = fmaxf(rmax[r], O0[r] * maskv[r]);
                rmax[r] = fmaxf(rmax[r], O1[r] * maskv[r]);
            }
        }
        __syncthreads();
    }

#pragma unroll
    for (int r = 0; r < 4; ++r)
#pragma unroll
        for (int dd = 1; dd < 16; dd <<= 1) rmax[r] = fmaxf(rmax[r], __shfl_xor(rmax[r], dd));
    if (ln == 0) {
#pragma unroll
        for (int r = 0; r < 4; ++r) red[sh * 32 + rowb + r] = rmax[r];
    }
    __syncthreads();
    if (tid < 32)
        wsrow[(size_t)b * T_DIM + t0 + tid] = fmaxf(red[tid], red[32 + tid]);
}

// ============ fallback (round-1, verified): K/V staged per block, Vt row-major ============
__global__ __launch_bounds__(256, 2)
void attn_band_mfma(const float* __restrict__ Q, const float* __restrict__ K,
                    const unsigned short* __restrict__ Vt,
                    const float* __restrict__ Mask, const int* __restrict__ m_ptr,
                    float* __restrict__ wsrow)
{
    __shared__ __align__(16) char smem_raw[57600];
    short* SM = (short*)smem_raw;
    short* Kc = SM;
    short* Qc = SM + 288 * KROW;
    short* P  = SM;
    short* Vl = SM + 32 * PROW;
    float* pmax = (float*)(smem_raw + 56832);
    float* psum = pmax + 64;
    float* red  = psum + 64;

    const int h = blockIdx.x;
    const int logical = (h & 7) * 64 + (h >> 3);
    const int b  = logical >> 6;
    const int t0 = (logical & 63) * TB;

    const int tid = threadIdx.x;
    const int w = tid >> 6, lane = tid & 63, g = lane >> 4, ln = lane & 15;
    const int th = w >> 1, sh = w & 1;
    const int m  = m_ptr[0];

    const int s_lo = max(0, t0 - m);
    const int s_hi = min(T_DIM - 1, t0 + TB - 1 + m);

    const float* Qb = Q + (size_t)b * T_DIM * C_DIM;
    const float* Kb = K + (size_t)b * T_DIM * C_DIM;
    const unsigned short* Vtb = Vt + (size_t)b * C_DIM * T_DIM;

    f32x4 E[9];
    f32x4 zed = {0.f, 0.f, 0.f, 0.f};
#pragma unroll
    for (int i = 0; i < 9; ++i) E[i] = zed;

    for (int cc = 0; cc < C_DIM / 64; ++cc) {
        const int c0 = cc * 64;
        __syncthreads();
        for (int u = tid; u < 288 * 8; u += 256) {
            const int su = u >> 3, un = u & 7;
            const int s = min(s_lo + su, T_DIM - 1);
            const float4* src = (const float4*)(Kb + (size_t)s * C_DIM + c0 + un * 8);
            float4 x = src[0], y = src[1];
            uint4 o; o.x = pk2(x.x, x.y); o.y = pk2(x.z, x.w);
            o.z = pk2(y.x, y.y); o.w = pk2(y.z, y.w);
            *(uint4*)(Kc + su * KROW + un * 8) = o;
        }
        {
            const int su = tid >> 3, un = tid & 7;
            const float4* src = (const float4*)(Qb + (size_t)(t0 + su) * C_DIM + c0 + un * 8);
            float4 x = src[0], y = src[1];
            uint4 o; o.x = pk2(x.x, x.y); o.y = pk2(x.z, x.w);
            o.z = pk2(y.x, y.y); o.w = pk2(y.z, y.w);
            *(uint4*)(Qc + su * KROW + un * 8) = o;
        }
        __syncthreads();
        s16x8 aq[2];
#pragma unroll
        for (int kk = 0; kk < 2; ++kk)
            aq[kk] = *(const s16x8*)(Qc + (th * 16 + ln) * KROW + kk * 32 + g * 8);
#pragma unroll
        for (int i = 0; i < 9; ++i) {
            const int srow2 = (sh * 9 + i) * 16 + ln;
#pragma unroll
            for (int kk = 0; kk < 2; ++kk) {
                s16x8 bk = *(const s16x8*)(Kc + srow2 * KROW + kk * 32 + g * 8);
                E[i] = __builtin_amdgcn_mfma_f32_16x16x32_bf16(aq[kk], bk, E[i], 0, 0, 0);
            }
        }
    }

    const float scale = 0.03125f;
    const int rowb = th * 16 + g * 4;
    float lm[4];
#pragma unroll
    for (int r = 0; r < 4; ++r) lm[r] = -INFINITY;
    const int s_base = s_lo + sh * 144 + ln;
#pragma unroll
    for (int i = 0; i < 9; ++i) {
        const int s = s_base + i * 16;
#pragma unroll
        for (int r = 0; r < 4; ++r) {
            const int t = t0 + rowb + r;
            int d = t - s; d = d < 0 ? -d : d;
            const bool valid = (s <= s_hi) && (d <= m);
            float e = valid ? E[i][r] : -INFINITY;
            E[i][r] = e;
            lm[r] = fmaxf(lm[r], e);
        }
    }
#pragma unroll
    for (int r = 0; r < 4; ++r)
#pragma unroll
        for (int dd = 1; dd < 16; dd <<= 1) lm[r] = fmaxf(lm[r], __shfl_xor(lm[r], dd));
    if (ln == 0) {
#pragma unroll
        for (int r = 0; r < 4; ++r) pmax[sh * 32 + rowb + r] = lm[r];
    }
    __syncthreads();
    float Mr[4], sum[4];
#pragma unroll
    for (int r = 0; r < 4; ++r) {
        Mr[r] = fmaxf(pmax[rowb + r], pmax[32 + rowb + r]) * scale;
        sum[r] = 0.f;
    }
#pragma unroll
    for (int i = 0; i < 9; ++i)
#pragma unroll
        for (int r = 0; r < 4; ++r) {
            float e = __expf(E[i][r] * scale - Mr[r]);
            E[i][r] = e;
            sum[r] += e;
        }
#pragma unroll
    for (int r = 0; r < 4; ++r)
#pragma unroll
        for (int dd = 1; dd < 16; dd <<= 1) sum[r] += __shfl_xor(sum[r], dd);
    if (ln == 0) {
#pragma unroll
        for (int r = 0; r < 4; ++r) psum[sh * 32 + rowb + r] = sum[r];
    }
    __syncthreads();
    float inv[4];
#pragma unroll
    for (int r = 0; r < 4; ++r) inv[r] = 1.0f / (psum[rowb + r] + psum[32 + rowb + r]);
#pragma unroll
    for (int i = 0; i < 9; ++i) {
        const int col = sh * 144 + i * 16 + ln;
#pragma unroll
        for (int r = 0; r < 4; ++r)
            P[(rowb + r) * PROW + col] = (short)f2bf(E[i][r] * inv[r]);
    }
    __syncthreads();

    s16x8 pa[9];
#pragma unroll
    for (int kg = 0; kg < 9; ++kg)
        pa[kg] = *(const s16x8*)(P + (th * 16 + ln) * PROW + kg * 32 + g * 8);

    float maskv[4], rmax[4];
#pragma unroll
    for (int r = 0; r < 4; ++r) {
        maskv[r] = Mask[(size_t)b * T_DIM + t0 + rowb + r];
        rmax[r]  = -INFINITY;
    }

    for (int cc = 0; cc < C_DIM / 64; ++cc) {
        __syncthreads();
        for (int i2 = tid; i2 < 64 * 36; i2 += 256) {
            const int cr = i2 / 36, un = i2 - cr * 36;
            const int sb = min(s_lo + un * 8, T_DIM - 8);
            uint4 x = *(const uint4*)(Vtb + (size_t)(cc * 64 + cr) * T_DIM + sb);
            *(uint4*)(Vl + cr * PROW + un * 8) = x;
        }
        __syncthreads();
#pragma unroll
        for (int nbi = 0; nbi < 2; ++nbi) {
            const int crow = sh * 32 + nbi * 16 + ln;
            f32x4 O = zed;
#pragma unroll
            for (int kg = 0; kg < 9; ++kg) {
                s16x8 bv = *(const s16x8*)(Vl + crow * PROW + kg * 32 + g * 8);
                O = __builtin_amdgcn_mfma_f32_16x16x32_bf16(pa[kg], bv, O, 0, 0, 0);
            }
#pragma unroll
            for (int r = 0; r < 4; ++r)
                rmax[r] = fmaxf(rmax[r], O[r] * maskv[r]);
        }
    }
#pragma unroll
    for (int r = 0; r < 4; ++r)
#pragma unroll
        for (int dd = 1; dd < 16; dd <<= 1) rmax[r] = fmaxf(rmax[r], __shfl_xor(rmax[r], dd));
    if (ln == 0) {
#pragma unroll
        for (int r = 0; r < 4; ++r) red[sh * 32 + rowb + r] = rmax[r];
    }
    __syncthreads();
    if (tid < 32)
        wsrow[(size_t)b * T_DIM + t0 + tid] = fmaxf(red[tid], red[32 + tid]);
}

// out[b] = sum_t ws[b][t]
__global__ void reduce_b(const float* __restrict__ ws, float* __restrict__ out)
{
    const int b = blockIdx.x;
    float s = 0.f;
    for (int t = threadIdx.x; t < T_DIM; t += 256) s += ws[(size_t)b * T_DIM + t];
#pragma unroll
    for (int dd = 32; dd > 0; dd >>= 1) s += __shfl_xor(s, dd);
    __shared__ float acc[4];
    if ((threadIdx.x & 63) == 0) acc[threadIdx.x >> 6] = s;
    __syncthreads();
    if (threadIdx.x == 0) out[b] = acc[0] + acc[1] + acc[2] + acc[3];
}

extern "C" void kernel_launch(void* const* d_in, const int* in_sizes, int n_in,
                              void* d_out, int out_size, void* d_ws, size_t ws_size,
                              hipStream_t stream)
{
    const float* Q    = (const float*)d_in[0];
    const float* K    = (const float*)d_in[1];
    const float* V    = (const float*)d_in[2];
    const float* Mask = (const float*)d_in[3];
    const int*   m    = (const int*)d_in[4];
    float* out = (float*)d_out;

    const size_t frag_bytes = (size_t)B_DIM * T_DIM * C_DIM * 2;   // 33,554,432 per tensor
    const size_t need_main  = 2 * frag_bytes + (size_t)B_DIM * T_DIM * 4;

    if (ws_size >= need_main) {
        unsigned short* Kt  = (unsigned short*)d_ws;
        unsigned short* Vtt = (unsigned short*)((char*)d_ws + frag_bytes);
        float* wsrow = (float*)((char*)d_ws + 2 * frag_bytes);
        tile_k<<<dim3(128, B_DIM), 256, 0, stream>>>(K, Kt);
        transpose_vx<<<dim3(T_DIM / 64, C_DIM / 64, B_DIM), 256, 0, stream>>>(V, Vtt, 1);
        attn_band_tiled<<<dim3((T_DIM / TB) * B_DIM), 256, 0, stream>>>(Q, Kt, Vtt, Mask, m, wsrow);
        reduce_b<<<B_DIM, 256, 0, stream>>>(wsrow, out);
    } else {
        unsigned short* Vt = (unsigned short*)d_ws;
        float* wsrow = (float*)((char*)d_ws + frag_bytes);
        transpose_vx<<<dim3(T_DIM / 64, C_DIM / 64, B_DIM), 256, 0, stream>>>(V, Vt, 0);
        attn_band_mfma<<<dim3((T_DIM / TB) * B_DIM), 256, 0, stream>>>(Q, K, Vt, Mask, m, wsrow);
        reduce_b<<<B_DIM, 256, 0, stream>>>(wsrow, out);
    }
}